// Round 14
// baseline (194.935 us; speedup 1.0000x reference)
//
#include <hip/hip_runtime.h>
#include <hip/hip_bf16.h>
#include <cstdint>
#include <cstddef>

#define NSAMP  64
#define NPT    16384
#define NLVL   4
#define NCHUNK 8
#define CHSZ   (NPT / NCHUNK)   // 2048 points per chunk

typedef __attribute__((ext_vector_type(8))) short  short8;
typedef __attribute__((ext_vector_type(4))) float  floatx4;
typedef __attribute__((ext_vector_type(4))) unsigned int uintx4;
typedef __attribute__((ext_vector_type(2))) unsigned int uintx2;

// fp32 -> bf16 RNE (finite values only)
__device__ __forceinline__ unsigned short f2bf(float x) {
    union { float f; unsigned int u; } c; c.f = x;
    unsigned int r = (c.u + 0x7fffu + ((c.u >> 16) & 1u)) >> 16;
    return (unsigned short)r;
}
__device__ __forceinline__ unsigned int f2bf2(float a, float b) {
    __hip_bfloat162 t = __float22bfloat162_rn(make_float2(a, b));
    union { __hip_bfloat162 h; unsigned int u; } c; c.h = t;
    return c.u;
}

// ---------------------------------------------------------------------------
// Kernel 1: LDS-staged chunked scan (r0 body) + PREP FOLDED IN (r9 win) +
// ROUND 14: DENSE ATOMIC-APPEND value lists.  For each hit, scan appends
// (h,u,v) into bufd[seed][level][0..63] via wave-aggregated atomicAdd on
// dcnt (one atomic per level-hit-iteration, ~3% of iters).  For kn<=64 the
// reference output is permutation+padding invariant (sample multiset = all
// hits + duplicates of an included hit; fmax over a multiset is exact), so
// arbitrary append order is BIT-IDENTICAL.  buf/cnts kept for the ordered
// slow path (kn>64, rare).  Early-exit interaction safe: break implies
// this chunk appended >=64 => dcnt>64 => slow path (except the
// single-chunk-exactly-64 case, where the appended set IS the smallest 64).
// dcnt zeroed via hipMemsetAsync before launch.
// ---------------------------------------------------------------------------
__global__ __launch_bounds__(512) void scan_kernel(
    const float* __restrict__ seedp, const float* __restrict__ pc,
    const float* __restrict__ rot, unsigned short* __restrict__ buf,
    int* __restrict__ cnts, int* __restrict__ dcnt, float* __restrict__ bufd,
    const float* __restrict__ w1, const float* __restrict__ b1, const float* __restrict__ g1,
    const float* __restrict__ be1, const float* __restrict__ m1, const float* __restrict__ v1,
    const float* __restrict__ w2, const float* __restrict__ b2, const float* __restrict__ g2,
    const float* __restrict__ be2, const float* __restrict__ m2, const float* __restrict__ v2,
    const float* __restrict__ w3, const float* __restrict__ b3, const float* __restrict__ g3,
    const float* __restrict__ be3, const float* __restrict__ m3, const float* __restrict__ v3,
    float* __restrict__ w1f, float* __restrict__ fb1,
    unsigned short* __restrict__ w2b, float* __restrict__ fb2,
    unsigned short* __restrict__ w3b, float* __restrict__ fb3)
{
    __shared__ float ch[CHSZ * 3];                 // 24576 B
    const int tid  = threadIdx.x;

    if (blockIdx.x >= 2048) {                      // ---- prep arm (64 blocks)
        const int t  = (blockIdx.x - 2048) * 512 + tid;
        const int nt = 64 * 512;
        const float eps = 1e-5f;
        for (int i = t; i < 64 * 3; i += nt)    w1f[i] = w1[i] * (g1[i / 3] / sqrtf(v1[i / 3] + eps));
        for (int i = t; i < 64; i += nt)        fb1[i] = (b1[i] - m1[i]) * (g1[i] / sqrtf(v1[i] + eps)) + be1[i];
        for (int i = t; i < 128 * 64; i += nt)  w2b[i] = f2bf(w2[i] * (g2[i / 64] / sqrtf(v2[i / 64] + eps)));
        for (int i = t; i < 128; i += nt)       fb2[i] = (b2[i] - m2[i]) * (g2[i] / sqrtf(v2[i] + eps)) + be2[i];
        for (int i = t; i < 256 * 128; i += nt) w3b[i] = f2bf(w3[i] * (g3[i / 128] / sqrtf(v3[i / 128] + eps)));
        for (int i = t; i < 256; i += nt)       fb3[i] = (b3[i] - m3[i]) * (g3[i] / sqrtf(v3[i] + eps)) + be3[i];
        return;
    }

    const int lane = tid & 63;
    const int w    = tid >> 6;                     // 0..7
    const int sg   = blockIdx.x >> 3;              // seed group 0..255
    const int c    = blockIdx.x & 7;               // chunk
    const int g    = sg * 8 + w;                   // seed 0..2047
    const int b    = g >> 10;

    {
        const float4* src = (const float4*)(pc + ((size_t)b * NPT + c * CHSZ) * 3);
        float4* dst = (float4*)ch;
        dst[tid]        = src[tid];
        dst[tid + 512]  = src[tid + 512];
        dst[tid + 1024] = src[tid + 1024];
    }
    __syncthreads();

    const float* sd = seedp + (size_t)g * 3;
    const float sx = sd[0], sy = sd[1], sz = sd[2];
    const float* R = rot + (size_t)g * 9;
    const float r00 = R[0], r01 = R[1], r02 = R[2];
    const float r10 = R[3], r11 = R[4], r12 = R[5];
    const float r20 = R[6], r21 = R[7], r22 = R[8];
    const float nc0 = -(sx * r00 + sy * r10 + sz * r20);
    const float nc1 = -(sx * r01 + sy * r11 + sz * r21);
    const float nc2 = -(sx * r02 + sy * r12 + sz * r22);

    unsigned short* bufg = buf + (size_t)g * (NLVL * NCHUNK * 64);
    int cnt0 = 0, cnt1 = 0, cnt2 = 0, cnt3 = 0;
    const unsigned long long lm = (1ull << lane) - 1ull;

    for (int bt = 0; bt < 4; ++bt) {               // 4 batches x 8 iters
        float pxv[8], pyv[8], pzv[8];
        #pragma unroll
        for (int j = 0; j < 8; ++j) {              // 24 LDS loads, batched
            const int pl = (bt * 8 + j) * 64 + lane;
            pxv[j] = ch[pl * 3];
            pyv[j] = ch[pl * 3 + 1];
            pzv[j] = ch[pl * 3 + 2];
        }
        #pragma unroll
        for (int j = 0; j < 8; ++j) {              // pure-VALU tests
            const float h = fmaf(pxv[j], r00, fmaf(pyv[j], r10, fmaf(pzv[j], r20, nc0)));
            const float u = fmaf(pxv[j], r01, fmaf(pyv[j], r11, fmaf(pzv[j], r21, nc1)));
            const float v = fmaf(pxv[j], r02, fmaf(pyv[j], r12, fmaf(pzv[j], r22, nc2)));
            const float r2 = fmaf(u, u, v * v);
            const bool base = (r2 < 0.0025f) && (h > -0.02f) && (h < 0.04f);

            const unsigned long long bal3 = __ballot(base);
            if (bal3 == 0ull) continue;            // ~97% of iterations

            const unsigned short pidx = (unsigned short)(c * CHSZ + (bt * 8 + j) * 64 + lane);
            #pragma unroll
            for (int l = 0; l < NLVL; ++l) {
                unsigned long long bal; bool m;
                if (l == 3) { m = base; bal = bal3; }
                else {
                    const float hm = (l == 0) ? 0.01f : (l == 1) ? 0.02f : 0.03f;
                    m = base && (h < hm);
                    bal = __ballot(m);
                }
                if (bal == 0ull) continue;
                int& cnt = (l == 0) ? cnt0 : (l == 1) ? cnt1 : (l == 2) ? cnt2 : cnt3;

                // wave-aggregated dense append (one atomic per wave)
                const int leader = (int)__ffsll((unsigned long long)bal) - 1;
                int gbase = 0;
                if (lane == leader)
                    gbase = atomicAdd(&dcnt[g * NLVL + l], (int)__popcll(bal));
                gbase = __shfl(gbase, leader);

                if (m) {
                    const int off = (int)__popcll(bal & lm);
                    const int pos = cnt + off;
                    if (pos < 64) bufg[(l * NCHUNK + c) * 64 + pos] = pidx;
                    const int gpos = gbase + off;
                    if (gpos < 64) {
                        float* vp = bufd + ((size_t)(g * NLVL + l) * 64 + gpos) * 3;
                        vp[0] = h; vp[1] = u; vp[2] = v;
                    }
                }
                cnt += (int)__popcll(bal);
            }
        }
        if (cnt0 >= NSAMP) break;                  // nested: level 0 fills last
    }

    if (lane == 0) {
        int* cg = cnts + (size_t)g * (NLVL * NCHUNK);
        cg[0 * NCHUNK + c] = cnt0;
        cg[1 * NCHUNK + c] = cnt1;
        cg[2 * NCHUNK + c] = cnt2;
        cg[3 * NCHUNK + c] = cnt3;
    }
}

// ---------------------------------------------------------------------------
// Kernel 2: ROUND 14 — fused MLP with DENSE 2-HOP GATHER (dc<=64, ~99% of
// levels including the gating level 3): 1 dcnt load -> 1 dense bufd load.
// No cnts walk, no buf hop, no pc scatter.  Padding = clamp(n, dc-1)
// (max-invariant: duplicates of an included value).  dc>64 / dc==0 keep
// the exact ordered r12 path.  r13's failure isolated the gate: the first
// barrier waits on the SLOWEST level's gather; level 3 was usually slow.
// ---------------------------------------------------------------------------
__global__ __launch_bounds__(256) void mlp_kernel(
    const float* __restrict__ seedp, const float* __restrict__ pc,
    const float* __restrict__ rot,
    const unsigned short* __restrict__ buf, const int* __restrict__ cnts,
    const int* __restrict__ dcnt, const float* __restrict__ bufd,
    const float* __restrict__ w1f, const float* __restrict__ fb1,
    const unsigned short* __restrict__ w2b, const float* __restrict__ fb2,
    const unsigned short* __restrict__ w3b, const float* __restrict__ fb3,
    float* __restrict__ out)
{
    __shared__ unsigned short h1t[4096];           // [8][64][8]    8 KB
    __shared__ unsigned short h2t[8192];           // [16][64][8]  16 KB
    __shared__ float xg[NLVL][3][64];              // gathered inputs  3 KB
    __shared__ int kn_sh[NLVL];

    const int tid = threadIdx.x;
    const int n      = tid & 63;                   // sample (= lane)
    const int w      = tid >> 6;
    const int lane15 = tid & 15;
    const int quad   = (tid & 63) >> 4;

    const int gb = blockIdx.x;                     // seed 0..2047
    const int b = gb >> 10, s = gb & 1023;

    // ---- block-start gather: wave w owns level w ----
    {
        const int l = w;
        const int dc0 = dcnt[gb * NLVL + l];
        if (n == 0) kn_sh[l] = dc0;
        if (dc0 > 0 && dc0 <= 64) {
            // FAST dense path: all hits appended; order/padding irrelevant.
            const int src = min(n, dc0 - 1);
            const float* vp = bufd + ((size_t)(gb * NLVL + l) * 64 + src) * 3;
            xg[l][0][n] = vp[0];
            xg[l][1][n] = vp[1];
            xg[l][2][n] = vp[2];
        } else {
            // SLOW (dc0>64) / EMPTY (dc0==0): exact ordered walk (r12 path)
            const int* cg = cnts + (size_t)gb * (NLVL * NCHUNK) + l * NCHUNK;
            const unsigned short* bl = buf + (size_t)gb * (NLVL * NCHUNK * 64) + l * (NCHUNK * 64);
            int selc = -1, selp = 0, acc = 0, firstc = -1;
            #pragma unroll
            for (int c = 0; c < NCHUNK; ++c) {
                const int cn = min(cg[c], 64);
                if (cn > 0 && firstc < 0) firstc = c;
                if (n >= acc && n < acc + cn) { selc = c; selp = n - acc; }
                acc += cn;
            }
            if (selc < 0) { selc = firstc; selp = 0; }
            int idx = 0;
            if (selc >= 0) idx = (int)bl[selc * 64 + selp];
            const float* sd = seedp + (size_t)gb * 3;
            const float* R  = rot   + (size_t)gb * 9;
            const float* pp = pc + ((size_t)b * NPT + idx) * 3;
            const float dx = pp[0] - sd[0], dy = pp[1] - sd[1], dz = pp[2] - sd[2];
            xg[l][0][n] = dx * R[0] + dy * R[3] + dz * R[6];
            xg[l][1][n] = dx * R[1] + dy * R[4] + dz * R[7];
            xg[l][2][n] = dx * R[2] + dy * R[5] + dz * R[8];
        }
    }

    // ---- weight caches (independent of gather; compiler interleaves) ----
    short8 wa3[4][4];
    float  wb3[4];
    #pragma unroll
    for (int mt = 0; mt < 4; ++mt) {
        const int m0 = (w * 4 + mt) * 16;
        #pragma unroll
        for (int k0 = 0; k0 < 4; ++k0)
            wa3[mt][k0] = *(const short8*)&w3b[(m0 + lane15) * 128 + k0 * 32 + quad * 8];
        wb3[mt] = fb3[m0 + lane15];
    }
    short8 a20[2], a21[2]; floatx4 b2v[2];
    #pragma unroll
    for (int mi = 0; mi < 2; ++mi) {
        const int m0 = (w * 2 + mi) * 16;
        a20[mi] = *(const short8*)&w2b[(m0 + lane15) * 64 + quad * 8];
        a21[mi] = *(const short8*)&w2b[(m0 + lane15) * 64 + 32 + quad * 8];
        b2v[mi] = *(const floatx4*)&fb2[m0 + quad * 4];
    }

    __syncthreads();   // xg + kn_sh visible to all waves

    // ---- F = number of fast levels (prefix by nesting), wave-uniform
    int F;
    {
        int fm = 0;
        #pragma unroll
        for (int l = 0; l < NLVL; ++l) fm += (kn_sh[l] <= 16) ? 1 : 0;
        F = __builtin_amdgcn_readfirstlane(fm);
    }

    if (F >= 1) {
        // =================== packed pass over levels 0..F-1 ===============
        {
            const int lvl = min(n >> 4, F - 1);
            const int sidx = n & 15;
            const float x0 = xg[lvl][0][sidx], x1 = xg[lvl][1][sidx], x2 = xg[lvl][2][sidx];
            unsigned int p[8];
            #pragma unroll
            for (int j = 0; j < 8; ++j) {
                const int o0 = __builtin_amdgcn_readfirstlane(w * 16 + 2 * j);
                const float a0 = fb1[o0]     + w1f[o0*3]*x0   + w1f[o0*3+1]*x1 + w1f[o0*3+2]*x2;
                const float a1 = fb1[o0 + 1] + w1f[o0*3+3]*x0 + w1f[o0*3+4]*x1 + w1f[o0*3+5]*x2;
                p[j] = f2bf2(fmaxf(a0, 0.f), fmaxf(a1, 0.f));
            }
            *(uintx4*)&h1t[(((w * 2)    ) * 64 + n) * 8] = (uintx4){p[0], p[1], p[2], p[3]};
            *(uintx4*)&h1t[(((w * 2) + 1) * 64 + n) * 8] = (uintx4){p[4], p[5], p[6], p[7]};
        }
        __syncthreads();

        // ---- L2 full width (r16 verbatim)
        {
            short8 bfr[4][2];
            #pragma unroll
            for (int nt = 0; nt < 4; ++nt)
                #pragma unroll
                for (int k0 = 0; k0 < 2; ++k0)
                    bfr[nt][k0] = *(const short8*)&h1t[((k0 * 4 + quad) * 64 + nt * 16 + lane15) * 8];

            #pragma unroll
            for (int mi = 0; mi < 2; ++mi) {
                const int m0 = (w * 2 + mi) * 16;
                #pragma unroll
                for (int nt = 0; nt < 4; ++nt) {
                    floatx4 acc = b2v[mi];
                    acc = __builtin_amdgcn_mfma_f32_16x16x32_bf16(a20[mi], bfr[nt][0], acc, 0, 0, 0);
                    acc = __builtin_amdgcn_mfma_f32_16x16x32_bf16(a21[mi], bfr[nt][1], acc, 0, 0, 0);
                    const int n2 = nt * 16 + lane15;
                    const unsigned int q0 = f2bf2(fmaxf(acc[0], 0.f), fmaxf(acc[1], 0.f));
                    const unsigned int q1 = f2bf2(fmaxf(acc[2], 0.f), fmaxf(acc[3], 0.f));
                    const int kb = (m0 >> 3) + (quad >> 1);
                    *(uintx2*)&h2t[(kb * 64 + n2) * 8 + (quad & 1) * 4] = (uintx2){q0, q1};
                }
            }
        }
        __syncthreads();

        // ---- L3 fragment reads (h2t -> regs)
        short8 bfr3[4][4];
        #pragma unroll
        for (int nt = 0; nt < 4; ++nt)
            #pragma unroll
            for (int k0 = 0; k0 < 4; ++k0)
                bfr3[nt][k0] = *(const short8*)&h2t[((k0 * 4 + quad) * 64 + nt * 16 + lane15) * 8];

        // ---- L1 for trailing level F (full width), overlaps L3 MFMA
        if (F < 4) {
            const float x0 = xg[F][0][n], x1 = xg[F][1][n], x2 = xg[F][2][n];
            unsigned int p[8];
            #pragma unroll
            for (int j = 0; j < 8; ++j) {
                const int o0 = __builtin_amdgcn_readfirstlane(w * 16 + 2 * j);
                const float a0 = fb1[o0]     + w1f[o0*3]*x0   + w1f[o0*3+1]*x1 + w1f[o0*3+2]*x2;
                const float a1 = fb1[o0 + 1] + w1f[o0*3+3]*x0 + w1f[o0*3+4]*x1 + w1f[o0*3+5]*x2;
                p[j] = f2bf2(fmaxf(a0, 0.f), fmaxf(a1, 0.f));
            }
            *(uintx4*)&h1t[(((w * 2)    ) * 64 + n) * 8] = (uintx4){p[0], p[1], p[2], p[3]};
            *(uintx4*)&h1t[(((w * 2) + 1) * 64 + n) * 8] = (uintx4){p[4], p[5], p[6], p[7]};
        }

        // ---- L3 full width, per-level (=per-nt) max, store levels < F
        #pragma unroll
        for (int mt = 0; mt < 4; ++mt) {
            floatx4 acc[4];
            #pragma unroll
            for (int nt = 0; nt < 4; ++nt) acc[nt] = (floatx4){0.f, 0.f, 0.f, 0.f};
            #pragma unroll
            for (int k0 = 0; k0 < 4; ++k0)
                #pragma unroll
                for (int nt = 0; nt < 4; ++nt)     // OPERANDS SWAPPED: D = H * W^T
                    acc[nt] = __builtin_amdgcn_mfma_f32_16x16x32_bf16(bfr3[nt][k0], wa3[mt][k0], acc[nt], 0, 0, 0);

            float tv[4];
            #pragma unroll
            for (int nt = 0; nt < 4; ++nt) {       // nt == level (for nt < F)
                float t = fmaxf(fmaxf(acc[nt][0], acc[nt][1]), fmaxf(acc[nt][2], acc[nt][3]));
                t = fmaxf(t, __shfl_xor(t, 16));
                t = fmaxf(t, __shfl_xor(t, 32));
                tv[nt] = fmaxf(t + wb3[mt], 0.f);
            }
            if (quad == 0) {
                const int o = (w * 4 + mt) * 16 + lane15;
                float* op = &out[(((size_t)b * 256 + o) * 1024 + s) * 4];
                if (F == 4) {
                    *(float4*)op = make_float4(tv[0], tv[1], tv[2], tv[3]);
                } else {
                    op[0] = tv[0];
                    if (F > 1) op[1] = tv[1];
                    if (F > 2) op[2] = tv[2];
                }
            }
        }

        // =================== trailing full levels l = F..3 =================
        for (int l = F; l < 4; ++l) {
            __syncthreads();   // h1t(l) visible; prior h2t reads drained

            // ---- L2 full (reads h1t, writes h2t) — r16 verbatim
            {
                short8 bfr[4][2];
                #pragma unroll
                for (int nt = 0; nt < 4; ++nt)
                    #pragma unroll
                    for (int k0 = 0; k0 < 2; ++k0)
                        bfr[nt][k0] = *(const short8*)&h1t[((k0 * 4 + quad) * 64 + nt * 16 + lane15) * 8];

                #pragma unroll
                for (int mi = 0; mi < 2; ++mi) {
                    const int m0 = (w * 2 + mi) * 16;
                    #pragma unroll
                    for (int nt = 0; nt < 4; ++nt) {
                        floatx4 acc = b2v[mi];
                        acc = __builtin_amdgcn_mfma_f32_16x16x32_bf16(a20[mi], bfr[nt][0], acc, 0, 0, 0);
                        acc = __builtin_amdgcn_mfma_f32_16x16x32_bf16(a21[mi], bfr[nt][1], acc, 0, 0, 0);
                        const int n2 = nt * 16 + lane15;
                        const unsigned int q0 = f2bf2(fmaxf(acc[0], 0.f), fmaxf(acc[1], 0.f));
                        const unsigned int q1 = f2bf2(fmaxf(acc[2], 0.f), fmaxf(acc[3], 0.f));
                        const int kb = (m0 >> 3) + (quad >> 1);
                        *(uintx2*)&h2t[(kb * 64 + n2) * 8 + (quad & 1) * 4] = (uintx2){q0, q1};
                    }
                }
            }
            __syncthreads();   // h2t(l) visible; h1t(l) reads drained

            // ---- L3 fragment reads
            short8 bfr3f[4][4];
            #pragma unroll
            for (int nt = 0; nt < 4; ++nt)
                #pragma unroll
                for (int k0 = 0; k0 < 4; ++k0)
                    bfr3f[nt][k0] = *(const short8*)&h2t[((k0 * 4 + quad) * 64 + nt * 16 + lane15) * 8];

            // ---- L1 for level l+1 (overlaps L3 MFMA)
            if (l < 3) {
                const float x0 = xg[l + 1][0][n], x1 = xg[l + 1][1][n], x2 = xg[l + 1][2][n];
                unsigned int p[8];
                #pragma unroll
                for (int j = 0; j < 8; ++j) {
                    const int o0 = __builtin_amdgcn_readfirstlane(w * 16 + 2 * j);
                    const float a0 = fb1[o0]     + w1f[o0*3]*x0   + w1f[o0*3+1]*x1 + w1f[o0*3+2]*x2;
                    const float a1 = fb1[o0 + 1] + w1f[o0*3+3]*x0 + w1f[o0*3+4]*x1 + w1f[o0*3+5]*x2;
                    p[j] = f2bf2(fmaxf(a0, 0.f), fmaxf(a1, 0.f));
                }
                *(uintx4*)&h1t[(((w * 2)    ) * 64 + n) * 8] = (uintx4){p[0], p[1], p[2], p[3]};
                *(uintx4*)&h1t[(((w * 2) + 1) * 64 + n) * 8] = (uintx4){p[4], p[5], p[6], p[7]};
            }

            // ---- L3 MFMA + epilogue (full-level scalar store at slot l)
            #pragma unroll
            for (int mt = 0; mt < 4; ++mt) {
                floatx4 acc[4];
                #pragma unroll
                for (int nt = 0; nt < 4; ++nt) acc[nt] = (floatx4){0.f, 0.f, 0.f, 0.f};
                #pragma unroll
                for (int k0 = 0; k0 < 4; ++k0)
                    #pragma unroll
                    for (int nt = 0; nt < 4; ++nt)   // OPERANDS SWAPPED: D = H * W^T
                        acc[nt] = __builtin_amdgcn_mfma_f32_16x16x32_bf16(bfr3f[nt][k0], wa3[mt][k0], acc[nt], 0, 0, 0);

                float t0 = fmaxf(fmaxf(acc[0][0], acc[0][1]), fmaxf(acc[0][2], acc[0][3]));
                float t1 = fmaxf(fmaxf(acc[1][0], acc[1][1]), fmaxf(acc[1][2], acc[1][3]));
                float t2 = fmaxf(fmaxf(acc[2][0], acc[2][1]), fmaxf(acc[2][2], acc[2][3]));
                float t3 = fmaxf(fmaxf(acc[3][0], acc[3][1]), fmaxf(acc[3][2], acc[3][3]));
                float t  = fmaxf(fmaxf(t0, t1), fmaxf(t2, t3));
                t = fmaxf(t, __shfl_xor(t, 16));
                t = fmaxf(t, __shfl_xor(t, 32));
                if (quad == 0) {
                    const int o = (w * 4 + mt) * 16 + lane15;
                    out[(((size_t)b * 256 + o) * 1024 + s) * 4 + l] = fmaxf(t + wb3[mt], 0.f);
                }
            }
        }
        return;
    }

    // =================== F == 0 (rare): full-only 4-phase loop =============
    {
        const float x0 = xg[0][0][n], x1 = xg[0][1][n], x2 = xg[0][2][n];
        unsigned int p[8];
        #pragma unroll
        for (int j = 0; j < 8; ++j) {
            const int o0 = __builtin_amdgcn_readfirstlane(w * 16 + 2 * j);
            const float a0 = fb1[o0]     + w1f[o0*3]*x0   + w1f[o0*3+1]*x1 + w1f[o0*3+2]*x2;
            const float a1 = fb1[o0 + 1] + w1f[o0*3+3]*x0 + w1f[o0*3+4]*x1 + w1f[o0*3+5]*x2;
            p[j] = f2bf2(fmaxf(a0, 0.f), fmaxf(a1, 0.f));
        }
        *(uintx4*)&h1t[(((w * 2)    ) * 64 + n) * 8] = (uintx4){p[0], p[1], p[2], p[3]};
        *(uintx4*)&h1t[(((w * 2) + 1) * 64 + n) * 8] = (uintx4){p[4], p[5], p[6], p[7]};
    }

    for (int it = 0; it < 4; ++it) {
        const int l = it;

        __syncthreads();

        {
            short8 bfr[4][2];
            #pragma unroll
            for (int nt = 0; nt < 4; ++nt)
                #pragma unroll
                for (int k0 = 0; k0 < 2; ++k0)
                    bfr[nt][k0] = *(const short8*)&h1t[((k0 * 4 + quad) * 64 + nt * 16 + lane15) * 8];

            #pragma unroll
            for (int mi = 0; mi < 2; ++mi) {
                const int m0 = (w * 2 + mi) * 16;
                #pragma unroll
                for (int nt = 0; nt < 4; ++nt) {
                    floatx4 acc = b2v[mi];
                    acc = __builtin_amdgcn_mfma_f32_16x16x32_bf16(a20[mi], bfr[nt][0], acc, 0, 0, 0);
                    acc = __builtin_amdgcn_mfma_f32_16x16x32_bf16(a21[mi], bfr[nt][1], acc, 0, 0, 0);
                    const int n2 = nt * 16 + lane15;
                    const unsigned int q0 = f2bf2(fmaxf(acc[0], 0.f), fmaxf(acc[1], 0.f));
                    const unsigned int q1 = f2bf2(fmaxf(acc[2], 0.f), fmaxf(acc[3], 0.f));
                    const int kb = (m0 >> 3) + (quad >> 1);
                    *(uintx2*)&h2t[(kb * 64 + n2) * 8 + (quad & 1) * 4] = (uintx2){q0, q1};
                }
            }
        }
        __syncthreads();

        short8 bfr3[4][4];
        #pragma unroll
        for (int nt = 0; nt < 4; ++nt)
            #pragma unroll
            for (int k0 = 0; k0 < 4; ++k0)
                bfr3[nt][k0] = *(const short8*)&h2t[((k0 * 4 + quad) * 64 + nt * 16 + lane15) * 8];

        if (it < 3) {
            const float x0 = xg[it + 1][0][n], x1 = xg[it + 1][1][n], x2 = xg[it + 1][2][n];
            unsigned int p[8];
            #pragma unroll
            for (int j = 0; j < 8; ++j) {
                const int o0 = __builtin_amdgcn_readfirstlane(w * 16 + 2 * j);
                const float a0 = fb1[o0]     + w1f[o0*3]*x0   + w1f[o0*3+1]*x1 + w1f[o0*3+2]*x2;
                const float a1 = fb1[o0 + 1] + w1f[o0*3+3]*x0 + w1f[o0*3+4]*x1 + w1f[o0*3+5]*x2;
                p[j] = f2bf2(fmaxf(a0, 0.f), fmaxf(a1, 0.f));
            }
            *(uintx4*)&h1t[(((w * 2)    ) * 64 + n) * 8] = (uintx4){p[0], p[1], p[2], p[3]};
            *(uintx4*)&h1t[(((w * 2) + 1) * 64 + n) * 8] = (uintx4){p[4], p[5], p[6], p[7]};
        }

        #pragma unroll
        for (int mt = 0; mt < 4; ++mt) {
            floatx4 acc[4];
            #pragma unroll
            for (int nt = 0; nt < 4; ++nt) acc[nt] = (floatx4){0.f, 0.f, 0.f, 0.f};
            #pragma unroll
            for (int k0 = 0; k0 < 4; ++k0)
                #pragma unroll
                for (int nt = 0; nt < 4; ++nt)   // OPERANDS SWAPPED: D = H * W^T
                    acc[nt] = __builtin_amdgcn_mfma_f32_16x16x32_bf16(bfr3[nt][k0], wa3[mt][k0], acc[nt], 0, 0, 0);

            float t0 = fmaxf(fmaxf(acc[0][0], acc[0][1]), fmaxf(acc[0][2], acc[0][3]));
            float t1 = fmaxf(fmaxf(acc[1][0], acc[1][1]), fmaxf(acc[1][2], acc[1][3]));
            float t2 = fmaxf(fmaxf(acc[2][0], acc[2][1]), fmaxf(acc[2][2], acc[2][3]));
            float t3 = fmaxf(fmaxf(acc[3][0], acc[3][1]), fmaxf(acc[3][2], acc[3][3]));
            float t  = fmaxf(fmaxf(t0, t1), fmaxf(t2, t3));
            t = fmaxf(t, __shfl_xor(t, 16));
            t = fmaxf(t, __shfl_xor(t, 32));
            if (quad == 0) {
                const int o = (w * 4 + mt) * 16 + lane15;
                out[(((size_t)b * 256 + o) * 1024 + s) * 4 + l] = fmaxf(t + wb3[mt], 0.f);
            }
        }
    }
}

// ---------------------------------------------------------------------------
// Workspace: w1f fl[192] fb1 fl[64] fb2 fl[128] fb3 fl[256]
//            w2b us[8192] w3b us[32768]
//            buf us[4,194,304] cnts int[65,536]
//            dcnt int[8,192] bufd fl[1,572,864]      (~15 MB total)
// ---------------------------------------------------------------------------
extern "C" void kernel_launch(void* const* d_in, const int* in_sizes, int n_in,
                              void* d_out, int out_size, void* d_ws, size_t ws_size,
                              hipStream_t stream) {
    const float* seed = (const float*)d_in[0];
    const float* pc   = (const float*)d_in[1];
    const float* rot  = (const float*)d_in[2];
    const float* w1 = (const float*)d_in[3];
    const float* b1 = (const float*)d_in[4];
    const float* g1 = (const float*)d_in[5];
    const float* be1 = (const float*)d_in[6];
    const float* m1 = (const float*)d_in[7];
    const float* v1 = (const float*)d_in[8];
    const float* w2 = (const float*)d_in[9];
    const float* b2 = (const float*)d_in[10];
    const float* g2 = (const float*)d_in[11];
    const float* be2 = (const float*)d_in[12];
    const float* m2 = (const float*)d_in[13];
    const float* v2 = (const float*)d_in[14];
    const float* w3 = (const float*)d_in[15];
    const float* b3 = (const float*)d_in[16];
    const float* g3 = (const float*)d_in[17];
    const float* be3 = (const float*)d_in[18];
    const float* m3 = (const float*)d_in[19];
    const float* v3 = (const float*)d_in[20];

    float* w1f = (float*)d_ws;                            // 192
    float* fb1 = w1f + 192;                               // 64
    float* fb2 = fb1 + 64;                                // 128
    float* fb3 = fb2 + 128;                               // 256
    unsigned short* w2b = (unsigned short*)(fb3 + 256);   // 8192
    unsigned short* w3b = w2b + 8192;                     // 32768
    unsigned short* buf = w3b + 32768;                    // 4,194,304
    int* cnts = (int*)(buf + 4194304);                    // 65,536
    int* dcnt = cnts + 65536;                             // 8,192
    float* bufd = (float*)(dcnt + 8192);                  // 1,572,864

    hipMemsetAsync(dcnt, 0, 8192 * sizeof(int), stream);  // atomic counters

    scan_kernel<<<2112, 512, 0, stream>>>(seed, pc, rot, buf, cnts, dcnt, bufd,
                                          w1, b1, g1, be1, m1, v1,
                                          w2, b2, g2, be2, m2, v2,
                                          w3, b3, g3, be3, m3, v3,
                                          w1f, fb1, w2b, fb2, w3b, fb3);
    mlp_kernel<<<2048, 256, 0, stream>>>(seed, pc, rot, buf, cnts, dcnt, bufd,
                                         w1f, fb1, w2b, fb2, w3b, fb3,
                                         (float*)d_out);
}

// Round 15
// 161.862 us; speedup vs baseline: 1.2043x; 1.2043x over previous
//
#include <hip/hip_runtime.h>
#include <hip/hip_bf16.h>
#include <cstdint>
#include <cstddef>

#define NSAMP  64
#define NPT    16384
#define NLVL   4
#define NCHUNK 8
#define CHSZ   (NPT / NCHUNK)   // 2048 points per chunk

typedef __attribute__((ext_vector_type(8))) short  short8;
typedef __attribute__((ext_vector_type(4))) float  floatx4;
typedef __attribute__((ext_vector_type(4))) unsigned int uintx4;
typedef __attribute__((ext_vector_type(2))) unsigned int uintx2;

// fp32 -> bf16 RNE (finite values only)
__device__ __forceinline__ unsigned short f2bf(float x) {
    union { float f; unsigned int u; } c; c.f = x;
    unsigned int r = (c.u + 0x7fffu + ((c.u >> 16) & 1u)) >> 16;
    return (unsigned short)r;
}
__device__ __forceinline__ unsigned int f2bf2(float a, float b) {
    __hip_bfloat162 t = __float22bfloat162_rn(make_float2(a, b));
    union { __hip_bfloat162 h; unsigned int u; } c; c.h = t;
    return c.u;
}

// ---------------------------------------------------------------------------
// FINAL (r15 = r13 exact revert; session best 164.0 us).
// Session floor analysis: total = ~100 us fixed harness overhead + ~4 us
// scan + ~60 us mlp.  mlp is LATENCY-bound, not pipe-bound (MfmaUtil ~10%,
// VALUBusy ~21%, occupancy ~14%): the floor is the serial
// gather->L1->bar->L2->bar->L3 phase chain at 4 blocks/CU.  Measured A/Bs:
//   - occupancy up (r11 uniform blocks): WORSE (write-amp + dup prologues)
//   - occupancy down (r9 2-seed): WORSE (TLP loss > prologue amortization)
//   - gather-chain shortening (r12 3-hop, r13 partial 2-hop, r14 full
//     dense 2-hop): mlp flat ~60-63 in all three => chain is not the gate
//   - extra dispatch boundaries cost ~8-10 us each (r9 prep-fold win,
//     r14 memset regression) => 2-dispatch composition is optimal.
// Work-reduction ladder (duplicates-can't-change-max insight) captured
// 69.5 -> ~60 us fused (r21/r22/r23 arms, all absmax-bit-identical).
// ---------------------------------------------------------------------------
__global__ __launch_bounds__(512) void scan_kernel(
    const float* __restrict__ seedp, const float* __restrict__ pc,
    const float* __restrict__ rot, unsigned short* __restrict__ buf,
    int* __restrict__ cnts, float* __restrict__ bufv,
    const float* __restrict__ w1, const float* __restrict__ b1, const float* __restrict__ g1,
    const float* __restrict__ be1, const float* __restrict__ m1, const float* __restrict__ v1,
    const float* __restrict__ w2, const float* __restrict__ b2, const float* __restrict__ g2,
    const float* __restrict__ be2, const float* __restrict__ m2, const float* __restrict__ v2,
    const float* __restrict__ w3, const float* __restrict__ b3, const float* __restrict__ g3,
    const float* __restrict__ be3, const float* __restrict__ m3, const float* __restrict__ v3,
    float* __restrict__ w1f, float* __restrict__ fb1,
    unsigned short* __restrict__ w2b, float* __restrict__ fb2,
    unsigned short* __restrict__ w3b, float* __restrict__ fb3)
{
    __shared__ float ch[CHSZ * 3];                 // 24576 B
    const int tid  = threadIdx.x;

    if (blockIdx.x >= 2048) {                      // ---- prep arm (64 blocks)
        const int t  = (blockIdx.x - 2048) * 512 + tid;
        const int nt = 64 * 512;
        const float eps = 1e-5f;
        for (int i = t; i < 64 * 3; i += nt)    w1f[i] = w1[i] * (g1[i / 3] / sqrtf(v1[i / 3] + eps));
        for (int i = t; i < 64; i += nt)        fb1[i] = (b1[i] - m1[i]) * (g1[i] / sqrtf(v1[i] + eps)) + be1[i];
        for (int i = t; i < 128 * 64; i += nt)  w2b[i] = f2bf(w2[i] * (g2[i / 64] / sqrtf(v2[i / 64] + eps)));
        for (int i = t; i < 128; i += nt)       fb2[i] = (b2[i] - m2[i]) * (g2[i] / sqrtf(v2[i] + eps)) + be2[i];
        for (int i = t; i < 256 * 128; i += nt) w3b[i] = f2bf(w3[i] * (g3[i / 128] / sqrtf(v3[i / 128] + eps)));
        for (int i = t; i < 256; i += nt)       fb3[i] = (b3[i] - m3[i]) * (g3[i] / sqrtf(v3[i] + eps)) + be3[i];
        return;
    }

    const int lane = tid & 63;
    const int w    = tid >> 6;                     // 0..7
    const int sg   = blockIdx.x >> 3;              // seed group 0..255
    const int c    = blockIdx.x & 7;               // chunk
    const int g    = sg * 8 + w;                   // seed 0..2047
    const int b    = g >> 10;

    {
        const float4* src = (const float4*)(pc + ((size_t)b * NPT + c * CHSZ) * 3);
        float4* dst = (float4*)ch;
        dst[tid]        = src[tid];
        dst[tid + 512]  = src[tid + 512];
        dst[tid + 1024] = src[tid + 1024];
    }
    __syncthreads();

    const float* sd = seedp + (size_t)g * 3;
    const float sx = sd[0], sy = sd[1], sz = sd[2];
    const float* R = rot + (size_t)g * 9;
    const float r00 = R[0], r01 = R[1], r02 = R[2];
    const float r10 = R[3], r11 = R[4], r12 = R[5];
    const float r20 = R[6], r21 = R[7], r22 = R[8];
    const float nc0 = -(sx * r00 + sy * r10 + sz * r20);
    const float nc1 = -(sx * r01 + sy * r11 + sz * r21);
    const float nc2 = -(sx * r02 + sy * r12 + sz * r22);

    unsigned short* bufg = buf + (size_t)g * (NLVL * NCHUNK * 64);
    float* bufvg = bufv + (size_t)g * (NLVL * NCHUNK * 16 * 3);
    int cnt0 = 0, cnt1 = 0, cnt2 = 0, cnt3 = 0;
    const unsigned long long lm = (1ull << lane) - 1ull;

    for (int bt = 0; bt < 4; ++bt) {               // 4 batches x 8 iters
        float pxv[8], pyv[8], pzv[8];
        #pragma unroll
        for (int j = 0; j < 8; ++j) {              // 24 LDS loads, batched
            const int pl = (bt * 8 + j) * 64 + lane;
            pxv[j] = ch[pl * 3];
            pyv[j] = ch[pl * 3 + 1];
            pzv[j] = ch[pl * 3 + 2];
        }
        #pragma unroll
        for (int j = 0; j < 8; ++j) {              // pure-VALU tests
            const float h = fmaf(pxv[j], r00, fmaf(pyv[j], r10, fmaf(pzv[j], r20, nc0)));
            const float u = fmaf(pxv[j], r01, fmaf(pyv[j], r11, fmaf(pzv[j], r21, nc1)));
            const float v = fmaf(pxv[j], r02, fmaf(pyv[j], r12, fmaf(pzv[j], r22, nc2)));
            const float r2 = fmaf(u, u, v * v);
            const bool base = (r2 < 0.0025f) && (h > -0.02f) && (h < 0.04f);

            const unsigned long long bal3 = __ballot(base);
            if (bal3 == 0ull) continue;            // ~97% of iterations

            const unsigned short pidx = (unsigned short)(c * CHSZ + (bt * 8 + j) * 64 + lane);
            #pragma unroll
            for (int l = 0; l < NLVL; ++l) {
                unsigned long long bal; bool m;
                if (l == 3) { m = base; bal = bal3; }
                else {
                    const float hm = (l == 0) ? 0.01f : (l == 1) ? 0.02f : 0.03f;
                    m = base && (h < hm);
                    bal = __ballot(m);
                }
                int& cnt = (l == 0) ? cnt0 : (l == 1) ? cnt1 : (l == 2) ? cnt2 : cnt3;
                if (m) {
                    const int pos = cnt + (int)__popcll(bal & lm);
                    if (pos < 64) bufg[(l * NCHUNK + c) * 64 + pos] = pidx;
                    if (pos < 16) {                // value store (fast-gather)
                        float* vp = bufvg + ((l * NCHUNK + c) * 16 + pos) * 3;
                        vp[0] = h; vp[1] = u; vp[2] = v;
                    }
                }
                cnt += (int)__popcll(bal);
            }
        }
        if (cnt0 >= NSAMP) break;                  // nested: level 0 fills last
    }

    if (lane == 0) {
        int* cg = cnts + (size_t)g * (NLVL * NCHUNK);
        cg[0 * NCHUNK + c] = cnt0;
        cg[1 * NCHUNK + c] = cnt1;
        cg[2 * NCHUNK + c] = cnt2;
        cg[3 * NCHUNK + c] = cnt3;
    }
}

// ---------------------------------------------------------------------------
// Kernel 2: fused MLP (r13 exact) — block-start wave-parallel gather with
// 2-hop bufv fast path for kn<=16 levels; prefix-packed level schedule.
// ---------------------------------------------------------------------------
__global__ __launch_bounds__(256) void mlp_kernel(
    const float* __restrict__ seedp, const float* __restrict__ pc,
    const float* __restrict__ rot,
    const unsigned short* __restrict__ buf, const int* __restrict__ cnts,
    const float* __restrict__ bufv,
    const float* __restrict__ w1f, const float* __restrict__ fb1,
    const unsigned short* __restrict__ w2b, const float* __restrict__ fb2,
    const unsigned short* __restrict__ w3b, const float* __restrict__ fb3,
    float* __restrict__ out)
{
    __shared__ unsigned short h1t[4096];           // [8][64][8]    8 KB
    __shared__ unsigned short h2t[8192];           // [16][64][8]  16 KB
    __shared__ float xg[NLVL][3][64];              // gathered inputs  3 KB
    __shared__ int kn_sh[NLVL];

    const int tid = threadIdx.x;
    const int n      = tid & 63;                   // sample (= lane)
    const int w      = tid >> 6;
    const int lane15 = tid & 15;
    const int quad   = (tid & 63) >> 4;

    const int gb = blockIdx.x;                     // seed 0..2047
    const int b = gb >> 10, s = gb & 1023;

    // ---- block-start gather: wave w owns level w ----
    {
        const int l = w;
        const int* cg = cnts + (size_t)gb * (NLVL * NCHUNK) + l * NCHUNK;
        int selc = -1, selp = 0, acc = 0, firstc = -1;
        #pragma unroll
        for (int c = 0; c < NCHUNK; ++c) {
            const int cn = min(cg[c], 64);
            if (cn > 0 && firstc < 0) firstc = c;
            if (n >= acc && n < acc + cn) { selc = c; selp = n - acc; }
            acc += cn;
        }
        if (selc < 0) { selc = firstc; selp = 0; }   // pad with first entry
        const int kn = acc;

        if (kn > 0 && kn <= 16) {
            // FAST: values precomputed by scan (2-hop chain)
            const float* vp = bufv + ((size_t)gb * (NLVL * NCHUNK) + l * NCHUNK + selc) * 48 + selp * 3;
            xg[l][0][n] = vp[0];
            xg[l][1][n] = vp[1];
            xg[l][2][n] = vp[2];
        } else {
            // SLOW (kn>16) / EMPTY (kn==0): index -> pc (r12 path)
            const unsigned short* bl = buf + (size_t)gb * (NLVL * NCHUNK * 64) + l * (NCHUNK * 64);
            int idx = 0;
            if (selc >= 0) idx = (int)bl[selc * 64 + selp];
            const float* sd = seedp + (size_t)gb * 3;
            const float* R  = rot   + (size_t)gb * 9;
            const float* pp = pc + ((size_t)b * NPT + idx) * 3;
            const float dx = pp[0] - sd[0], dy = pp[1] - sd[1], dz = pp[2] - sd[2];
            xg[l][0][n] = dx * R[0] + dy * R[3] + dz * R[6];
            xg[l][1][n] = dx * R[1] + dy * R[4] + dz * R[7];
            xg[l][2][n] = dx * R[2] + dy * R[5] + dz * R[8];
        }
        if (n == 0) kn_sh[l] = kn;
    }

    // ---- weight caches (independent of gather; compiler interleaves) ----
    short8 wa3[4][4];
    float  wb3[4];
    #pragma unroll
    for (int mt = 0; mt < 4; ++mt) {
        const int m0 = (w * 4 + mt) * 16;
        #pragma unroll
        for (int k0 = 0; k0 < 4; ++k0)
            wa3[mt][k0] = *(const short8*)&w3b[(m0 + lane15) * 128 + k0 * 32 + quad * 8];
        wb3[mt] = fb3[m0 + lane15];
    }
    short8 a20[2], a21[2]; floatx4 b2v[2];
    #pragma unroll
    for (int mi = 0; mi < 2; ++mi) {
        const int m0 = (w * 2 + mi) * 16;
        a20[mi] = *(const short8*)&w2b[(m0 + lane15) * 64 + quad * 8];
        a21[mi] = *(const short8*)&w2b[(m0 + lane15) * 64 + 32 + quad * 8];
        b2v[mi] = *(const floatx4*)&fb2[m0 + quad * 4];
    }

    __syncthreads();   // xg + kn_sh visible to all waves

    // ---- F = number of fast levels (prefix by nesting), wave-uniform
    int F;
    {
        int fm = 0;
        #pragma unroll
        for (int l = 0; l < NLVL; ++l) fm += (kn_sh[l] <= 16) ? 1 : 0;
        F = __builtin_amdgcn_readfirstlane(fm);
    }

    if (F >= 1) {
        // =================== packed pass over levels 0..F-1 ===============
        {
            const int lvl = min(n >> 4, F - 1);
            const int sidx = n & 15;
            const float x0 = xg[lvl][0][sidx], x1 = xg[lvl][1][sidx], x2 = xg[lvl][2][sidx];
            unsigned int p[8];
            #pragma unroll
            for (int j = 0; j < 8; ++j) {
                const int o0 = __builtin_amdgcn_readfirstlane(w * 16 + 2 * j);
                const float a0 = fb1[o0]     + w1f[o0*3]*x0   + w1f[o0*3+1]*x1 + w1f[o0*3+2]*x2;
                const float a1 = fb1[o0 + 1] + w1f[o0*3+3]*x0 + w1f[o0*3+4]*x1 + w1f[o0*3+5]*x2;
                p[j] = f2bf2(fmaxf(a0, 0.f), fmaxf(a1, 0.f));
            }
            *(uintx4*)&h1t[(((w * 2)    ) * 64 + n) * 8] = (uintx4){p[0], p[1], p[2], p[3]};
            *(uintx4*)&h1t[(((w * 2) + 1) * 64 + n) * 8] = (uintx4){p[4], p[5], p[6], p[7]};
        }
        __syncthreads();

        // ---- L2 full width (r16 verbatim)
        {
            short8 bfr[4][2];
            #pragma unroll
            for (int nt = 0; nt < 4; ++nt)
                #pragma unroll
                for (int k0 = 0; k0 < 2; ++k0)
                    bfr[nt][k0] = *(const short8*)&h1t[((k0 * 4 + quad) * 64 + nt * 16 + lane15) * 8];

            #pragma unroll
            for (int mi = 0; mi < 2; ++mi) {
                const int m0 = (w * 2 + mi) * 16;
                #pragma unroll
                for (int nt = 0; nt < 4; ++nt) {
                    floatx4 acc = b2v[mi];
                    acc = __builtin_amdgcn_mfma_f32_16x16x32_bf16(a20[mi], bfr[nt][0], acc, 0, 0, 0);
                    acc = __builtin_amdgcn_mfma_f32_16x16x32_bf16(a21[mi], bfr[nt][1], acc, 0, 0, 0);
                    const int n2 = nt * 16 + lane15;
                    const unsigned int q0 = f2bf2(fmaxf(acc[0], 0.f), fmaxf(acc[1], 0.f));
                    const unsigned int q1 = f2bf2(fmaxf(acc[2], 0.f), fmaxf(acc[3], 0.f));
                    const int kb = (m0 >> 3) + (quad >> 1);
                    *(uintx2*)&h2t[(kb * 64 + n2) * 8 + (quad & 1) * 4] = (uintx2){q0, q1};
                }
            }
        }
        __syncthreads();

        // ---- L3 fragment reads (h2t -> regs)
        short8 bfr3[4][4];
        #pragma unroll
        for (int nt = 0; nt < 4; ++nt)
            #pragma unroll
            for (int k0 = 0; k0 < 4; ++k0)
                bfr3[nt][k0] = *(const short8*)&h2t[((k0 * 4 + quad) * 64 + nt * 16 + lane15) * 8];

        // ---- L1 for trailing level F (full width), overlaps L3 MFMA
        if (F < 4) {
            const float x0 = xg[F][0][n], x1 = xg[F][1][n], x2 = xg[F][2][n];
            unsigned int p[8];
            #pragma unroll
            for (int j = 0; j < 8; ++j) {
                const int o0 = __builtin_amdgcn_readfirstlane(w * 16 + 2 * j);
                const float a0 = fb1[o0]     + w1f[o0*3]*x0   + w1f[o0*3+1]*x1 + w1f[o0*3+2]*x2;
                const float a1 = fb1[o0 + 1] + w1f[o0*3+3]*x0 + w1f[o0*3+4]*x1 + w1f[o0*3+5]*x2;
                p[j] = f2bf2(fmaxf(a0, 0.f), fmaxf(a1, 0.f));
            }
            *(uintx4*)&h1t[(((w * 2)    ) * 64 + n) * 8] = (uintx4){p[0], p[1], p[2], p[3]};
            *(uintx4*)&h1t[(((w * 2) + 1) * 64 + n) * 8] = (uintx4){p[4], p[5], p[6], p[7]};
        }

        // ---- L3 full width, per-level (=per-nt) max, store levels < F
        #pragma unroll
        for (int mt = 0; mt < 4; ++mt) {
            floatx4 acc[4];
            #pragma unroll
            for (int nt = 0; nt < 4; ++nt) acc[nt] = (floatx4){0.f, 0.f, 0.f, 0.f};
            #pragma unroll
            for (int k0 = 0; k0 < 4; ++k0)
                #pragma unroll
                for (int nt = 0; nt < 4; ++nt)     // OPERANDS SWAPPED: D = H * W^T
                    acc[nt] = __builtin_amdgcn_mfma_f32_16x16x32_bf16(bfr3[nt][k0], wa3[mt][k0], acc[nt], 0, 0, 0);

            float tv[4];
            #pragma unroll
            for (int nt = 0; nt < 4; ++nt) {       // nt == level (for nt < F)
                float t = fmaxf(fmaxf(acc[nt][0], acc[nt][1]), fmaxf(acc[nt][2], acc[nt][3]));
                t = fmaxf(t, __shfl_xor(t, 16));
                t = fmaxf(t, __shfl_xor(t, 32));
                tv[nt] = fmaxf(t + wb3[mt], 0.f);
            }
            if (quad == 0) {
                const int o = (w * 4 + mt) * 16 + lane15;
                float* op = &out[(((size_t)b * 256 + o) * 1024 + s) * 4];
                if (F == 4) {
                    *(float4*)op = make_float4(tv[0], tv[1], tv[2], tv[3]);
                } else {
                    op[0] = tv[0];
                    if (F > 1) op[1] = tv[1];
                    if (F > 2) op[2] = tv[2];
                }
            }
        }

        // =================== trailing full levels l = F..3 =================
        for (int l = F; l < 4; ++l) {
            __syncthreads();   // h1t(l) visible; prior h2t reads drained

            // ---- L2 full (reads h1t, writes h2t) — r16 verbatim
            {
                short8 bfr[4][2];
                #pragma unroll
                for (int nt = 0; nt < 4; ++nt)
                    #pragma unroll
                    for (int k0 = 0; k0 < 2; ++k0)
                        bfr[nt][k0] = *(const short8*)&h1t[((k0 * 4 + quad) * 64 + nt * 16 + lane15) * 8];

                #pragma unroll
                for (int mi = 0; mi < 2; ++mi) {
                    const int m0 = (w * 2 + mi) * 16;
                    #pragma unroll
                    for (int nt = 0; nt < 4; ++nt) {
                        floatx4 acc = b2v[mi];
                        acc = __builtin_amdgcn_mfma_f32_16x16x32_bf16(a20[mi], bfr[nt][0], acc, 0, 0, 0);
                        acc = __builtin_amdgcn_mfma_f32_16x16x32_bf16(a21[mi], bfr[nt][1], acc, 0, 0, 0);
                        const int n2 = nt * 16 + lane15;
                        const unsigned int q0 = f2bf2(fmaxf(acc[0], 0.f), fmaxf(acc[1], 0.f));
                        const unsigned int q1 = f2bf2(fmaxf(acc[2], 0.f), fmaxf(acc[3], 0.f));
                        const int kb = (m0 >> 3) + (quad >> 1);
                        *(uintx2*)&h2t[(kb * 64 + n2) * 8 + (quad & 1) * 4] = (uintx2){q0, q1};
                    }
                }
            }
            __syncthreads();   // h2t(l) visible; h1t(l) reads drained

            // ---- L3 fragment reads
            short8 bfr3f[4][4];
            #pragma unroll
            for (int nt = 0; nt < 4; ++nt)
                #pragma unroll
                for (int k0 = 0; k0 < 4; ++k0)
                    bfr3f[nt][k0] = *(const short8*)&h2t[((k0 * 4 + quad) * 64 + nt * 16 + lane15) * 8];

            // ---- L1 for level l+1 (overlaps L3 MFMA)
            if (l < 3) {
                const float x0 = xg[l + 1][0][n], x1 = xg[l + 1][1][n], x2 = xg[l + 1][2][n];
                unsigned int p[8];
                #pragma unroll
                for (int j = 0; j < 8; ++j) {
                    const int o0 = __builtin_amdgcn_readfirstlane(w * 16 + 2 * j);
                    const float a0 = fb1[o0]     + w1f[o0*3]*x0   + w1f[o0*3+1]*x1 + w1f[o0*3+2]*x2;
                    const float a1 = fb1[o0 + 1] + w1f[o0*3+3]*x0 + w1f[o0*3+4]*x1 + w1f[o0*3+5]*x2;
                    p[j] = f2bf2(fmaxf(a0, 0.f), fmaxf(a1, 0.f));
                }
                *(uintx4*)&h1t[(((w * 2)    ) * 64 + n) * 8] = (uintx4){p[0], p[1], p[2], p[3]};
                *(uintx4*)&h1t[(((w * 2) + 1) * 64 + n) * 8] = (uintx4){p[4], p[5], p[6], p[7]};
            }

            // ---- L3 MFMA + epilogue (full-level scalar store at slot l)
            #pragma unroll
            for (int mt = 0; mt < 4; ++mt) {
                floatx4 acc[4];
                #pragma unroll
                for (int nt = 0; nt < 4; ++nt) acc[nt] = (floatx4){0.f, 0.f, 0.f, 0.f};
                #pragma unroll
                for (int k0 = 0; k0 < 4; ++k0)
                    #pragma unroll
                    for (int nt = 0; nt < 4; ++nt)   // OPERANDS SWAPPED: D = H * W^T
                        acc[nt] = __builtin_amdgcn_mfma_f32_16x16x32_bf16(bfr3f[nt][k0], wa3[mt][k0], acc[nt], 0, 0, 0);

                float t0 = fmaxf(fmaxf(acc[0][0], acc[0][1]), fmaxf(acc[0][2], acc[0][3]));
                float t1 = fmaxf(fmaxf(acc[1][0], acc[1][1]), fmaxf(acc[1][2], acc[1][3]));
                float t2 = fmaxf(fmaxf(acc[2][0], acc[2][1]), fmaxf(acc[2][2], acc[2][3]));
                float t3 = fmaxf(fmaxf(acc[3][0], acc[3][1]), fmaxf(acc[3][2], acc[3][3]));
                float t  = fmaxf(fmaxf(t0, t1), fmaxf(t2, t3));
                t = fmaxf(t, __shfl_xor(t, 16));
                t = fmaxf(t, __shfl_xor(t, 32));
                if (quad == 0) {
                    const int o = (w * 4 + mt) * 16 + lane15;
                    out[(((size_t)b * 256 + o) * 1024 + s) * 4 + l] = fmaxf(t + wb3[mt], 0.f);
                }
            }
        }
        return;
    }

    // =================== F == 0 (rare): full-only 4-phase loop =============
    {
        const float x0 = xg[0][0][n], x1 = xg[0][1][n], x2 = xg[0][2][n];
        unsigned int p[8];
        #pragma unroll
        for (int j = 0; j < 8; ++j) {
            const int o0 = __builtin_amdgcn_readfirstlane(w * 16 + 2 * j);
            const float a0 = fb1[o0]     + w1f[o0*3]*x0   + w1f[o0*3+1]*x1 + w1f[o0*3+2]*x2;
            const float a1 = fb1[o0 + 1] + w1f[o0*3+3]*x0 + w1f[o0*3+4]*x1 + w1f[o0*3+5]*x2;
            p[j] = f2bf2(fmaxf(a0, 0.f), fmaxf(a1, 0.f));
        }
        *(uintx4*)&h1t[(((w * 2)    ) * 64 + n) * 8] = (uintx4){p[0], p[1], p[2], p[3]};
        *(uintx4*)&h1t[(((w * 2) + 1) * 64 + n) * 8] = (uintx4){p[4], p[5], p[6], p[7]};
    }

    for (int it = 0; it < 4; ++it) {
        const int l = it;

        __syncthreads();

        {
            short8 bfr[4][2];
            #pragma unroll
            for (int nt = 0; nt < 4; ++nt)
                #pragma unroll
                for (int k0 = 0; k0 < 2; ++k0)
                    bfr[nt][k0] = *(const short8*)&h1t[((k0 * 4 + quad) * 64 + nt * 16 + lane15) * 8];

            #pragma unroll
            for (int mi = 0; mi < 2; ++mi) {
                const int m0 = (w * 2 + mi) * 16;
                #pragma unroll
                for (int nt = 0; nt < 4; ++nt) {
                    floatx4 acc = b2v[mi];
                    acc = __builtin_amdgcn_mfma_f32_16x16x32_bf16(a20[mi], bfr[nt][0], acc, 0, 0, 0);
                    acc = __builtin_amdgcn_mfma_f32_16x16x32_bf16(a21[mi], bfr[nt][1], acc, 0, 0, 0);
                    const int n2 = nt * 16 + lane15;
                    const unsigned int q0 = f2bf2(fmaxf(acc[0], 0.f), fmaxf(acc[1], 0.f));
                    const unsigned int q1 = f2bf2(fmaxf(acc[2], 0.f), fmaxf(acc[3], 0.f));
                    const int kb = (m0 >> 3) + (quad >> 1);
                    *(uintx2*)&h2t[(kb * 64 + n2) * 8 + (quad & 1) * 4] = (uintx2){q0, q1};
                }
            }
        }
        __syncthreads();

        short8 bfr3[4][4];
        #pragma unroll
        for (int nt = 0; nt < 4; ++nt)
            #pragma unroll
            for (int k0 = 0; k0 < 4; ++k0)
                bfr3[nt][k0] = *(const short8*)&h2t[((k0 * 4 + quad) * 64 + nt * 16 + lane15) * 8];

        if (it < 3) {
            const float x0 = xg[it + 1][0][n], x1 = xg[it + 1][1][n], x2 = xg[it + 1][2][n];
            unsigned int p[8];
            #pragma unroll
            for (int j = 0; j < 8; ++j) {
                const int o0 = __builtin_amdgcn_readfirstlane(w * 16 + 2 * j);
                const float a0 = fb1[o0]     + w1f[o0*3]*x0   + w1f[o0*3+1]*x1 + w1f[o0*3+2]*x2;
                const float a1 = fb1[o0 + 1] + w1f[o0*3+3]*x0 + w1f[o0*3+4]*x1 + w1f[o0*3+5]*x2;
                p[j] = f2bf2(fmaxf(a0, 0.f), fmaxf(a1, 0.f));
            }
            *(uintx4*)&h1t[(((w * 2)    ) * 64 + n) * 8] = (uintx4){p[0], p[1], p[2], p[3]};
            *(uintx4*)&h1t[(((w * 2) + 1) * 64 + n) * 8] = (uintx4){p[4], p[5], p[6], p[7]};
        }

        #pragma unroll
        for (int mt = 0; mt < 4; ++mt) {
            floatx4 acc[4];
            #pragma unroll
            for (int nt = 0; nt < 4; ++nt) acc[nt] = (floatx4){0.f, 0.f, 0.f, 0.f};
            #pragma unroll
            for (int k0 = 0; k0 < 4; ++k0)
                #pragma unroll
                for (int nt = 0; nt < 4; ++nt)   // OPERANDS SWAPPED: D = H * W^T
                    acc[nt] = __builtin_amdgcn_mfma_f32_16x16x32_bf16(bfr3[nt][k0], wa3[mt][k0], acc[nt], 0, 0, 0);

            float t0 = fmaxf(fmaxf(acc[0][0], acc[0][1]), fmaxf(acc[0][2], acc[0][3]));
            float t1 = fmaxf(fmaxf(acc[1][0], acc[1][1]), fmaxf(acc[1][2], acc[1][3]));
            float t2 = fmaxf(fmaxf(acc[2][0], acc[2][1]), fmaxf(acc[2][2], acc[2][3]));
            float t3 = fmaxf(fmaxf(acc[3][0], acc[3][1]), fmaxf(acc[3][2], acc[3][3]));
            float t  = fmaxf(fmaxf(t0, t1), fmaxf(t2, t3));
            t = fmaxf(t, __shfl_xor(t, 16));
            t = fmaxf(t, __shfl_xor(t, 32));
            if (quad == 0) {
                const int o = (w * 4 + mt) * 16 + lane15;
                out[(((size_t)b * 256 + o) * 1024 + s) * 4 + l] = fmaxf(t + wb3[mt], 0.f);
            }
        }
    }
}

// ---------------------------------------------------------------------------
// Workspace: w1f fl[192] fb1 fl[64] fb2 fl[128] fb3 fl[256]
//            w2b us[8192] w3b us[32768]
//            buf us[4,194,304] cnts int[65,536]
//            bufv fl[3,145,728]                     (~21.3 MB total)
// ---------------------------------------------------------------------------
extern "C" void kernel_launch(void* const* d_in, const int* in_sizes, int n_in,
                              void* d_out, int out_size, void* d_ws, size_t ws_size,
                              hipStream_t stream) {
    const float* seed = (const float*)d_in[0];
    const float* pc   = (const float*)d_in[1];
    const float* rot  = (const float*)d_in[2];
    const float* w1 = (const float*)d_in[3];
    const float* b1 = (const float*)d_in[4];
    const float* g1 = (const float*)d_in[5];
    const float* be1 = (const float*)d_in[6];
    const float* m1 = (const float*)d_in[7];
    const float* v1 = (const float*)d_in[8];
    const float* w2 = (const float*)d_in[9];
    const float* b2 = (const float*)d_in[10];
    const float* g2 = (const float*)d_in[11];
    const float* be2 = (const float*)d_in[12];
    const float* m2 = (const float*)d_in[13];
    const float* v2 = (const float*)d_in[14];
    const float* w3 = (const float*)d_in[15];
    const float* b3 = (const float*)d_in[16];
    const float* g3 = (const float*)d_in[17];
    const float* be3 = (const float*)d_in[18];
    const float* m3 = (const float*)d_in[19];
    const float* v3 = (const float*)d_in[20];

    float* w1f = (float*)d_ws;                            // 192
    float* fb1 = w1f + 192;                               // 64
    float* fb2 = fb1 + 64;                                // 128
    float* fb3 = fb2 + 128;                               // 256
    unsigned short* w2b = (unsigned short*)(fb3 + 256);   // 8192
    unsigned short* w3b = w2b + 8192;                     // 32768
    unsigned short* buf = w3b + 32768;                    // 4,194,304
    int* cnts = (int*)(buf + 4194304);                    // 65,536
    float* bufv = (float*)(cnts + 65536);                 // 3,145,728

    scan_kernel<<<2112, 512, 0, stream>>>(seed, pc, rot, buf, cnts, bufv,
                                          w1, b1, g1, be1, m1, v1,
                                          w2, b2, g2, be2, m2, v2,
                                          w3, b3, g3, be3, m3, v3,
                                          w1f, fb1, w2b, fb2, w3b, fb3);
    mlp_kernel<<<2048, 256, 0, stream>>>(seed, pc, rot, buf, cnts, bufv,
                                         w1f, fb1, w2b, fb2, w3b, fb3,
                                         (float*)d_out);
}